// Round 1
// 606.429 us; speedup vs baseline: 1.1057x; 1.1057x over previous
//
#include <hip/hip_runtime.h>

// CrissCrossAttention on MI355X (gfx950), fp16-MFMA pipeline, fp32 accumulate.
//
// Pipeline (5 launches, all on `stream`):
//   1) qkv_gemm  : qkv[b,192,p] = fp16( qkv_w @ x + qkv_b )          (MFMA f16)
//   2) transpose : qkvT[b,o,w,h] = qkv[b,o,h,w]                      (LDS tile)
//   3) cc_attn   : z=0 horizontal (qkvT -> attn_hT), z=1 vertical (qkv -> attn_v)
//                  E = Q K^T (MFMA), softmax fp32 in-register, P V (MFMA)
//   4) transpose : attn_h[b,c,h,w] = attn_hT[b,c,w,h]
//   5) out_proj  : out = gamma * (out_w @ (attn_h+attn_v)) + out_b + x  (MFMA)
//
// R1 changes vs baseline (670 us):
//   - out_proj: MFMA operands swapped (A=S-tile, B=W) so the C-layout puts
//     4 consecutive p in each thread's acc regs -> float4 residual load +
//     float4 store (was 32+32 scalar dwords/thread; kernel was latency-bound
//     at 2.8 TB/s with FETCH+WRITE already minimal).
//   - qkv_gemm: grid (3,128,8)->(128,8) with in-block loop over the 3 m-tiles
//     (X tile staged once, x read exactly once from HBM), same operand swap
//     -> 8-byte f16x4 stores.
//
// Workspace layout (needs 144 MiB):
//   qkv   48 MB | qkvT 48 MB | attn_hT 16 MB | attn_h 16 MB | attn_v 16 MB

typedef _Float16 f16;
typedef _Float16 f16x4 __attribute__((ext_vector_type(4)));
typedef _Float16 f16x8 __attribute__((ext_vector_type(8)));
typedef float f32x4 __attribute__((ext_vector_type(4)));

#define MFMA16(a, b, c) __builtin_amdgcn_mfma_f32_16x16x32_f16(a, b, c, 0, 0, 0)

constexpr int CIN = 512;
constexpr int COUT = 64;       // per q/k/v
constexpr int HW = 128;
constexpr int P = HW * HW;     // 16384 pixels per batch
constexpr int QKV_CH = 192;

// ---------------------------------------------------------------------------
// Kernel 1: QKV projection GEMM.  C[192m x 128n] per block, K=512 in 32-chunks.
// grid (128 ntiles, 8 b), block 256 (4 waves, 2x2 wave grid), m-loop inside.
// MFMA operand order: A = X fragment (p rows), B = W fragment (m rows), so
// D[row=quad*4+r -> p][col=l15 -> m]: per-thread 4 consecutive p -> f16x4 store.
// ---------------------------------------------------------------------------
__global__ __launch_bounds__(256) void qkv_gemm(
    const float* __restrict__ x, const float* __restrict__ w,
    const float* __restrict__ bias, f16* __restrict__ qkv)
{
  // Wl: [192 m][32 k] stride 40 (pad breaks 16-way read conflicts)
  // Xt: [128 p][32 k] transposed, stride 40, XOR-swizzled columns
  __shared__ __attribute__((aligned(16))) f16 Wl[QKV_CH * 40];
  __shared__ __attribute__((aligned(16))) f16 Xt[128 * 40];
  const int p0 = blockIdx.x * 128;
  const int b = blockIdx.y;
  const float* xb = x + (size_t)b * CIN * P;
  const int t = threadIdx.x;
  const int lane = t & 63, wv = t >> 6;
  const int quad = lane >> 4, l15 = lane & 15;
  const int wm = (wv >> 1) * 32, wn = (wv & 1) * 64;

  f32x4 acc[3][4][2] = {};   // [m-tile][p-sub][m-sub]
  for (int k0 = 0; k0 < CIN; k0 += 32) {
    // stage W tile 192x32 (row-major, fp32->fp16)
    for (int it = 0; it < 6; ++it) {
      int c = t + it * 256;            // 1536 chunks of 4
      int row = c >> 3, c4 = (c & 7) * 4;
      const float4 v = *(const float4*)(w + (size_t)row * CIN + k0 + c4);
      f16* d = &Wl[row * 40 + c4];
      d[0] = (f16)v.x; d[1] = (f16)v.y; d[2] = (f16)v.z; d[3] = (f16)v.w;
    }
    // stage X tile 32k x 128p, transposed into Xt[p][k] with column swizzle
    for (int it = 0; it < 4; ++it) {
      int c = t + it * 256;            // 1024 chunks of 4
      int kr = c >> 5, p4 = (c & 31) * 4;
      const float4 v = *(const float4*)(xb + (size_t)(k0 + kr) * P + p0 + p4);
      float vv[4] = {v.x, v.y, v.z, v.w};
#pragma unroll
      for (int j = 0; j < 4; ++j) {
        int p = p4 + j;
        int kc = kr ^ (((p >> 3) & 3) << 3);
        Xt[p * 40 + kc] = (f16)vv[j];
      }
    }
    __syncthreads();
    f16x8 xf[4];
#pragma unroll
    for (int ps = 0; ps < 4; ++ps) {
      int pr = wn + ps * 16 + l15;
      int kb = (quad * 8) ^ (((pr >> 3) & 3) << 3);
      xf[ps] = *(const f16x8*)&Xt[pr * 40 + kb];
    }
#pragma unroll
    for (int mt = 0; mt < 3; ++mt) {
      f16x8 wf[2];
#pragma unroll
      for (int ms = 0; ms < 2; ++ms)
        wf[ms] = *(const f16x8*)&Wl[(mt * 64 + wm + ms * 16 + l15) * 40 + quad * 8];
#pragma unroll
      for (int ps = 0; ps < 4; ++ps)
#pragma unroll
        for (int ms = 0; ms < 2; ++ms)
          acc[mt][ps][ms] = MFMA16(xf[ps], wf[ms], acc[mt][ps][ms]);
    }
    __syncthreads();
  }
  f16* ob = qkv + (size_t)b * QKV_CH * P;
#pragma unroll
  for (int mt = 0; mt < 3; ++mt) {
#pragma unroll
    for (int ms = 0; ms < 2; ++ms) {
      int m = mt * 64 + wm + ms * 16 + l15;
      float bi = bias[m];
#pragma unroll
      for (int ps = 0; ps < 4; ++ps) {
        int p = p0 + wn + ps * 16 + quad * 4;
        f16x4 tmp;
#pragma unroll
        for (int r = 0; r < 4; ++r) tmp[r] = (f16)(acc[mt][ps][ms][r] + bi);
        *(f16x4*)(ob + (size_t)m * P + p) = tmp;
      }
    }
  }
}

// ---------------------------------------------------------------------------
// Kernel 2/4: spatial 128x128 transpose per channel plane, 64x64 tiles.
// grid (planes, 2, 2), block 256.
// ---------------------------------------------------------------------------
__global__ __launch_bounds__(256) void transpose_hw(
    const f16* __restrict__ in, f16* __restrict__ out)
{
  __shared__ __attribute__((aligned(16))) f16 T[64 * 72];
  const size_t plane = blockIdx.x;
  const int r0 = blockIdx.y * 64, c0 = blockIdx.z * 64;
  const f16* ip = in + plane * P;
  f16* op = out + plane * P;
  const int t = threadIdx.x;
  for (int it = 0; it < 2; ++it) {
    int c = t + it * 256;              // 512 chunks of 8
    int row = c >> 3, c8 = (c & 7) * 8;
    *(f16x8*)&T[row * 72 + c8] =
        *(const f16x8*)(ip + (size_t)(r0 + row) * HW + c0 + c8);
  }
  __syncthreads();
  for (int it = 0; it < 2; ++it) {
    int c = t + it * 256;
    int wr = c >> 3, h8 = (c & 7) * 8;
    f16 tmp[8];
#pragma unroll
    for (int j = 0; j < 8; ++j) tmp[j] = T[(h8 + j) * 72 + wr];
    *(f16x8*)(op + (size_t)(c0 + wr) * HW + r0 + h8) = *(const f16x8*)tmp;
  }
}

// ---------------------------------------------------------------------------
// Kernel 3: criss-cross attention over one line (row or column).
// grid (128 s, 8 b, 2 branch), block 256 (4 waves, each owns a 16-q strip).
// Input slice layout (both branches): elem(o, j) = src[b*192*P + o*P + s*128 + j]
// E[64q x 64k] = sum_j Q[q,j] K[k,j]  -> softmax over k -> O = P V [64q x 128j]
// ---------------------------------------------------------------------------
__global__ __launch_bounds__(256) void cc_attn(
    const f16* __restrict__ qkvT, const f16* __restrict__ qkvN,
    f16* __restrict__ outT, f16* __restrict__ outN)
{
  // Ql/Kl: [64 ch][128 j] stride 136; Vt: [128 j][64 k] stride 72 swizzled.
  // Al (P matrix, [64 q][64 k] stride 72) aliases Ql after E-phase.
  __shared__ __attribute__((aligned(16))) f16 smem[64 * 136 * 2 + 128 * 72];
  f16* Ql = smem;
  f16* Kl = smem + 64 * 136;
  f16* Vt = smem + 2 * 64 * 136;
  f16* Al = smem;  // alias of Ql
  const int s = blockIdx.x, b = blockIdx.y;
  const f16* src = blockIdx.z ? qkvN : qkvT;
  f16* dst = blockIdx.z ? outN : outT;
  const f16* base = src + (size_t)b * QKV_CH * P + (size_t)s * HW;
  const int t = threadIdx.x;
  const int lane = t & 63, wv = t >> 6;
  const int quad = lane >> 4, l15 = lane & 15;

  // stage Q, K (natural) and V (transposed+swizzled): 1024 chunks of 8 each
  for (int it = 0; it < 4; ++it) {
    int c = t + it * 256;
    int row = c >> 4, c8 = (c & 15) * 8;
    *(f16x8*)&Ql[row * 136 + c8] = *(const f16x8*)(base + (size_t)row * P + c8);
    *(f16x8*)&Kl[row * 136 + c8] =
        *(const f16x8*)(base + (size_t)(64 + row) * P + c8);
    f16x8 v = *(const f16x8*)(base + (size_t)(128 + row) * P + c8);
#pragma unroll
    for (int j = 0; j < 8; ++j) {
      int h = c8 + j;
      int kc = row ^ (((h >> 3) & 7) << 3);
      Vt[h * 72 + kc] = v[j];
    }
  }
  __syncthreads();

  const int m0 = wv * 16;  // this wave's q-strip
  f32x4 e[4] = {};
#pragma unroll
  for (int kk = 0; kk < 4; ++kk) {
    f16x8 aq = *(const f16x8*)&Ql[(m0 + l15) * 136 + kk * 32 + quad * 8];
#pragma unroll
    for (int nt = 0; nt < 4; ++nt) {
      f16x8 bk = *(const f16x8*)&Kl[(nt * 16 + l15) * 136 + kk * 32 + quad * 8];
      e[nt] = MFMA16(aq, bk, e[nt]);
    }
  }
  // softmax: lane holds E[q = m0+quad*4+r][k = nt*16+l15]; rows span 16 lanes
  float pr[4][4];
  float rinv[4];
#pragma unroll
  for (int r = 0; r < 4; ++r) {
    float mx = fmaxf(fmaxf(e[0][r], e[1][r]), fmaxf(e[2][r], e[3][r]));
    for (int off = 1; off < 16; off <<= 1) mx = fmaxf(mx, __shfl_xor(mx, off));
    float sm = 0.f;
#pragma unroll
    for (int nt = 0; nt < 4; ++nt) {
      float pv = __expf(e[nt][r] - mx);
      pr[nt][r] = pv;
      sm += pv;
    }
    for (int off = 1; off < 16; off <<= 1) sm += __shfl_xor(sm, off);
    rinv[r] = 1.0f / sm;
  }
  __syncthreads();  // all Q reads done before overwriting Al(=Ql)
#pragma unroll
  for (int nt = 0; nt < 4; ++nt)
#pragma unroll
    for (int r = 0; r < 4; ++r)
      Al[(m0 + quad * 4 + r) * 72 + nt * 16 + l15] = (f16)(pr[nt][r] * rinv[r]);
  __syncthreads();

  f32x4 o[8] = {};
#pragma unroll
  for (int kk = 0; kk < 2; ++kk) {
    f16x8 ap = *(const f16x8*)&Al[(m0 + l15) * 72 + kk * 32 + quad * 8];
#pragma unroll
    for (int nt = 0; nt < 8; ++nt) {
      int hr = nt * 16 + l15;
      int kb = (kk * 32 + quad * 8) ^ (((hr >> 3) & 7) << 3);
      f16x8 bv = *(const f16x8*)&Vt[hr * 72 + kb];
      o[nt] = MFMA16(ap, bv, o[nt]);
    }
  }
  f16* db = dst + (size_t)b * COUT * P + (size_t)s * HW;
#pragma unroll
  for (int nt = 0; nt < 8; ++nt)
#pragma unroll
    for (int r = 0; r < 4; ++r)
      db[(size_t)(m0 + quad * 4 + r) * P + nt * 16 + l15] = (f16)o[nt][r];
}

// ---------------------------------------------------------------------------
// Kernel 5: out projection + bias + gamma + residual.
// C[64m x 128n] per block, K=64. grid (8 mtiles, 128 ntiles, 8 b), block 256.
// MFMA operand order: A = S fragment (p rows), B = W fragment (m rows), so
// D[row=quad*4+r -> p][col=l15 -> m]: per-thread 4 consecutive p.
// Epilogue is float4 residual-load + float4 store (was scalar; latency-bound).
// ---------------------------------------------------------------------------
__global__ __launch_bounds__(256) void out_proj(
    const f16* __restrict__ ah, const f16* __restrict__ av,
    const float* __restrict__ w, const float* __restrict__ bias,
    const float* __restrict__ gamma_p, const float* __restrict__ x,
    float* __restrict__ out)
{
  __shared__ __attribute__((aligned(16))) f16 Wl[64 * 72];
  __shared__ __attribute__((aligned(16))) f16 St[128 * 72];
  const int m0 = blockIdx.x * 64;
  const int p0 = blockIdx.y * 128;
  const int b = blockIdx.z;
  const int t = threadIdx.x;
  const int lane = t & 63, wv = t >> 6;
  const int quad = lane >> 4, l15 = lane & 15;
  const int wm = (wv >> 1) * 32, wn = (wv & 1) * 64;

  // stage W: 64m x 64k (out_w is [512][64], contraction over its 2nd dim)
  for (int it = 0; it < 4; ++it) {
    int c = t + it * 256;              // 1024 chunks of 4
    int row = c >> 4, c4 = (c & 15) * 4;
    const float4 v = *(const float4*)(w + (size_t)(m0 + row) * COUT + c4);
    f16* d = &Wl[row * 72 + c4];
    d[0] = (f16)v.x; d[1] = (f16)v.y; d[2] = (f16)v.z; d[3] = (f16)v.w;
  }
  // stage S = attn_h + attn_v, transposed into St[p][k] with column swizzle
  const size_t abase = (size_t)b * COUT * P + p0;
  for (int it = 0; it < 4; ++it) {
    int c = t + it * 256;              // 1024 chunks of 8
    int k = c >> 4, p8 = (c & 15) * 8;
    f16x8 a = *(const f16x8*)(ah + abase + (size_t)k * P + p8);
    f16x8 vv = *(const f16x8*)(av + abase + (size_t)k * P + p8);
#pragma unroll
    for (int j = 0; j < 8; ++j) {
      int p = p8 + j;
      int kc = k ^ (((p >> 3) & 7) << 3);
      St[p * 72 + kc] = (f16)(a[j] + vv[j]);
    }
  }
  __syncthreads();

  f32x4 acc[4][2] = {};   // [p-sub][m-sub]
#pragma unroll
  for (int kk = 0; kk < 2; ++kk) {
    f16x8 sf[4], wf[2];
#pragma unroll
    for (int ps = 0; ps < 4; ++ps) {
      int pr2 = wn + ps * 16 + l15;
      int kb = (kk * 32 + quad * 8) ^ (((pr2 >> 3) & 7) << 3);
      sf[ps] = *(const f16x8*)&St[pr2 * 72 + kb];
    }
#pragma unroll
    for (int ms = 0; ms < 2; ++ms)
      wf[ms] = *(const f16x8*)&Wl[(wm + ms * 16 + l15) * 72 + kk * 32 + quad * 8];
#pragma unroll
    for (int ps = 0; ps < 4; ++ps)
#pragma unroll
      for (int ms = 0; ms < 2; ++ms)
        acc[ps][ms] = MFMA16(sf[ps], wf[ms], acc[ps][ms]);
  }
  const float g = *gamma_p;
  const float* xb = x + (size_t)b * CIN * P;
  float* ob = out + (size_t)b * CIN * P;
#pragma unroll
  for (int ms = 0; ms < 2; ++ms) {
    int m = m0 + wm + ms * 16 + l15;
    float bi = bias[m];
#pragma unroll
    for (int ps = 0; ps < 4; ++ps) {
      int p = p0 + wn + ps * 16 + quad * 4;
      size_t idx = (size_t)m * P + p;
      const float4 xv = *(const float4*)(xb + idx);
      float4 ov;
      ov.x = g * acc[ps][ms][0] + bi + xv.x;
      ov.y = g * acc[ps][ms][1] + bi + xv.y;
      ov.z = g * acc[ps][ms][2] + bi + xv.z;
      ov.w = g * acc[ps][ms][3] + bi + xv.w;
      *(float4*)(ob + idx) = ov;
    }
  }
}

// ---------------------------------------------------------------------------
extern "C" void kernel_launch(void* const* d_in, const int* in_sizes, int n_in,
                              void* d_out, int out_size, void* d_ws,
                              size_t ws_size, hipStream_t stream)
{
  (void)in_sizes; (void)n_in; (void)out_size; (void)ws_size;
  const float* x = (const float*)d_in[0];
  const float* qkv_w = (const float*)d_in[1];
  const float* qkv_b = (const float*)d_in[2];
  const float* out_w = (const float*)d_in[3];
  const float* out_b = (const float*)d_in[4];
  const float* gamma = (const float*)d_in[5];
  float* out = (float*)d_out;

  char* ws = (char*)d_ws;
  const size_t QKV_BYTES = (size_t)8 * QKV_CH * P * sizeof(f16);   // 48 MiB
  const size_t ATT_BYTES = (size_t)8 * COUT * P * sizeof(f16);     // 16 MiB
  f16* qkv  = (f16*)ws;
  f16* qkvT = (f16*)(ws + QKV_BYTES);
  f16* ahT  = (f16*)(ws + 2 * QKV_BYTES);
  f16* ahN  = (f16*)(ws + 2 * QKV_BYTES + ATT_BYTES);
  f16* avN  = (f16*)(ws + 2 * QKV_BYTES + 2 * ATT_BYTES);

  qkv_gemm<<<dim3(128, 8), 256, 0, stream>>>(x, qkv_w, qkv_b, qkv);
  transpose_hw<<<dim3(8 * QKV_CH, 2, 2), 256, 0, stream>>>(qkv, qkvT);
  cc_attn<<<dim3(128, 8, 2), 256, 0, stream>>>(qkvT, qkv, ahT, avN);
  transpose_hw<<<dim3(8 * COUT, 2, 2), 256, 0, stream>>>(ahT, ahN);
  out_proj<<<dim3(8, 128, 8), 256, 0, stream>>>(ahN, avN, out_w, out_b, gamma,
                                                x, out);
}

// Round 2
// 601.654 us; speedup vs baseline: 1.1145x; 1.0079x over previous
//
#include <hip/hip_runtime.h>

// CrissCrossAttention on MI355X (gfx950), fp16-MFMA pipeline, fp32 accumulate.
//
// Pipeline (5 launches, all on `stream`):
//   1) qkv_gemm  : qkv[b,192,p] = fp16( qkv_w @ x + qkv_b )          (MFMA f16)
//   2) transpose : qkvT[b,o,w,h] = qkv[b,o,h,w]                      (LDS tile)
//   3) cc_attn   : z=0 horizontal (qkvT -> attn_hT), z=1 vertical (qkv -> attn_v)
//   4) transpose : attn_h[b,c,h,w] = attn_hT[b,c,w,h]
//   5) out_proj  : out = gamma * (out_w @ (attn_h+attn_v)) + out_b + x  (MFMA)
//
// R2 changes vs R1 (606 us):
//   - cc_attn: Q fragments loaded straight from global into regs (wave-private
//     rows, issued before K/V staging); Al reuses the dead Kl region -> LDS
//     53->36 KB -> 4 blocks/CU (launch_bounds(256,4)); Al is wave-private so
//     no barrier between P-write and PV; output bounced through LDS
//     (XOR-swizzle, 2-way max) -> f16x8 coalesced stores (was 32x scalar 2B).
//   - out_proj: m-tile loop inside the block (grid (128,8)); S fragments
//     hoisted to 32 regs once; W fragments converted from global fp32 (L2-hot)
//     -> no Wl LDS, zero barriers in the m-loop; 4 blocks/CU exact residency.
//
// Workspace layout (needs 144 MiB):
//   qkv   48 MB | qkvT 48 MB | attn_hT 16 MB | attn_h 16 MB | attn_v 16 MB

typedef _Float16 f16;
typedef _Float16 f16x4 __attribute__((ext_vector_type(4)));
typedef _Float16 f16x8 __attribute__((ext_vector_type(8)));
typedef float f32x4 __attribute__((ext_vector_type(4)));

#define MFMA16(a, b, c) __builtin_amdgcn_mfma_f32_16x16x32_f16(a, b, c, 0, 0, 0)

constexpr int CIN = 512;
constexpr int COUT = 64;       // per q/k/v
constexpr int HW = 128;
constexpr int P = HW * HW;     // 16384 pixels per batch
constexpr int QKV_CH = 192;

// ---------------------------------------------------------------------------
// Kernel 1: QKV projection GEMM.  C[192m x 128n] per block, K=512 in 32-chunks.
// grid (128 ntiles, 8 b), block 256 (4 waves, 2x2 wave grid), m-loop inside.
// MFMA operand order: A = X fragment (p rows), B = W fragment (m rows), so
// D[row=quad*4+r -> p][col=l15 -> m]: per-thread 4 consecutive p -> f16x4 store.
// ---------------------------------------------------------------------------
__global__ __launch_bounds__(256) void qkv_gemm(
    const float* __restrict__ x, const float* __restrict__ w,
    const float* __restrict__ bias, f16* __restrict__ qkv)
{
  // Wl: [192 m][32 k] stride 40 (pad breaks 16-way read conflicts)
  // Xt: [128 p][32 k] transposed, stride 40, XOR-swizzled columns
  __shared__ __attribute__((aligned(16))) f16 Wl[QKV_CH * 40];
  __shared__ __attribute__((aligned(16))) f16 Xt[128 * 40];
  const int p0 = blockIdx.x * 128;
  const int b = blockIdx.y;
  const float* xb = x + (size_t)b * CIN * P;
  const int t = threadIdx.x;
  const int lane = t & 63, wv = t >> 6;
  const int quad = lane >> 4, l15 = lane & 15;
  const int wm = (wv >> 1) * 32, wn = (wv & 1) * 64;

  f32x4 acc[3][4][2] = {};   // [m-tile][p-sub][m-sub]
  for (int k0 = 0; k0 < CIN; k0 += 32) {
    // stage W tile 192x32 (row-major, fp32->fp16)
    for (int it = 0; it < 6; ++it) {
      int c = t + it * 256;            // 1536 chunks of 4
      int row = c >> 3, c4 = (c & 7) * 4;
      const float4 v = *(const float4*)(w + (size_t)row * CIN + k0 + c4);
      f16* d = &Wl[row * 40 + c4];
      d[0] = (f16)v.x; d[1] = (f16)v.y; d[2] = (f16)v.z; d[3] = (f16)v.w;
    }
    // stage X tile 32k x 128p, transposed into Xt[p][k] with column swizzle
    for (int it = 0; it < 4; ++it) {
      int c = t + it * 256;            // 1024 chunks of 4
      int kr = c >> 5, p4 = (c & 31) * 4;
      const float4 v = *(const float4*)(xb + (size_t)(k0 + kr) * P + p0 + p4);
      float vv[4] = {v.x, v.y, v.z, v.w};
#pragma unroll
      for (int j = 0; j < 4; ++j) {
        int p = p4 + j;
        int kc = kr ^ (((p >> 3) & 3) << 3);
        Xt[p * 40 + kc] = (f16)vv[j];
      }
    }
    __syncthreads();
    f16x8 xf[4];
#pragma unroll
    for (int ps = 0; ps < 4; ++ps) {
      int pr = wn + ps * 16 + l15;
      int kb = (quad * 8) ^ (((pr >> 3) & 3) << 3);
      xf[ps] = *(const f16x8*)&Xt[pr * 40 + kb];
    }
#pragma unroll
    for (int mt = 0; mt < 3; ++mt) {
      f16x8 wf[2];
#pragma unroll
      for (int ms = 0; ms < 2; ++ms)
        wf[ms] = *(const f16x8*)&Wl[(mt * 64 + wm + ms * 16 + l15) * 40 + quad * 8];
#pragma unroll
      for (int ps = 0; ps < 4; ++ps)
#pragma unroll
        for (int ms = 0; ms < 2; ++ms)
          acc[mt][ps][ms] = MFMA16(xf[ps], wf[ms], acc[mt][ps][ms]);
    }
    __syncthreads();
  }
  f16* ob = qkv + (size_t)b * QKV_CH * P;
#pragma unroll
  for (int mt = 0; mt < 3; ++mt) {
#pragma unroll
    for (int ms = 0; ms < 2; ++ms) {
      int m = mt * 64 + wm + ms * 16 + l15;
      float bi = bias[m];
#pragma unroll
      for (int ps = 0; ps < 4; ++ps) {
        int p = p0 + wn + ps * 16 + quad * 4;
        f16x4 tmp;
#pragma unroll
        for (int r = 0; r < 4; ++r) tmp[r] = (f16)(acc[mt][ps][ms][r] + bi);
        *(f16x4*)(ob + (size_t)m * P + p) = tmp;
      }
    }
  }
}

// ---------------------------------------------------------------------------
// Kernel 2/4: spatial 128x128 transpose per channel plane, 64x64 tiles.
// grid (planes, 2, 2), block 256.
// ---------------------------------------------------------------------------
__global__ __launch_bounds__(256) void transpose_hw(
    const f16* __restrict__ in, f16* __restrict__ out)
{
  __shared__ __attribute__((aligned(16))) f16 T[64 * 72];
  const size_t plane = blockIdx.x;
  const int r0 = blockIdx.y * 64, c0 = blockIdx.z * 64;
  const f16* ip = in + plane * P;
  f16* op = out + plane * P;
  const int t = threadIdx.x;
  for (int it = 0; it < 2; ++it) {
    int c = t + it * 256;              // 512 chunks of 8
    int row = c >> 3, c8 = (c & 7) * 8;
    *(f16x8*)&T[row * 72 + c8] =
        *(const f16x8*)(ip + (size_t)(r0 + row) * HW + c0 + c8);
  }
  __syncthreads();
  for (int it = 0; it < 2; ++it) {
    int c = t + it * 256;
    int wr = c >> 3, h8 = (c & 7) * 8;
    f16 tmp[8];
#pragma unroll
    for (int j = 0; j < 8; ++j) tmp[j] = T[(h8 + j) * 72 + wr];
    *(f16x8*)(op + (size_t)(c0 + wr) * HW + r0 + h8) = *(const f16x8*)tmp;
  }
}

// ---------------------------------------------------------------------------
// Kernel 3: criss-cross attention over one line (row or column).
// grid (128 s, 8 b, 2 branch), block 256 (4 waves, each owns a 16-q strip).
// Input slice layout (both branches): elem(o, j) = src[b*192*P + o*P + s*128 + j]
// E[64q x 64k] = sum_j Q[q,j] K[k,j]  -> softmax over k -> O = P V [64q x 128j]
// LDS: Kl 64x136 (K; reused as Al stride 72 after E, then Ol stride 136 after
// PV), Vt 128x72 swizzled.  Total 35.8 KB -> 4 blocks/CU.
// ---------------------------------------------------------------------------
__global__ __launch_bounds__(256, 4) void cc_attn(
    const f16* __restrict__ qkvT, const f16* __restrict__ qkvN,
    f16* __restrict__ outT, f16* __restrict__ outN)
{
  __shared__ __attribute__((aligned(16))) f16 smem[64 * 136 + 128 * 72];
  f16* Kl = smem;
  f16* Vt = smem + 64 * 136;
  f16* Al = smem;  // reuse of Kl region after E (wave-private rows)
  f16* Ol = smem;  // reuse of Kl region after PV (wave-private rows)
  const int s = blockIdx.x, b = blockIdx.y;
  const f16* src = blockIdx.z ? qkvN : qkvT;
  f16* dst = blockIdx.z ? outN : outT;
  const f16* base = src + (size_t)b * QKV_CH * P + (size_t)s * HW;
  const int t = threadIdx.x;
  const int lane = t & 63, wv = t >> 6;
  const int quad = lane >> 4, l15 = lane & 15;
  const int m0 = wv * 16;  // this wave's q-strip

  // Q fragments straight from global into regs (wave-private rows m0..m0+15).
  f16x8 aq[4];
#pragma unroll
  for (int kk = 0; kk < 4; ++kk)
    aq[kk] = *(const f16x8*)(base + (size_t)(m0 + l15) * P + kk * 32 + quad * 8);

  // stage K (natural) and V (transposed+swizzled): 1024 chunks of 8 each
  for (int it = 0; it < 4; ++it) {
    int c = t + it * 256;
    int row = c >> 4, c8 = (c & 15) * 8;
    *(f16x8*)&Kl[row * 136 + c8] =
        *(const f16x8*)(base + (size_t)(64 + row) * P + c8);
    f16x8 v = *(const f16x8*)(base + (size_t)(128 + row) * P + c8);
#pragma unroll
    for (int j = 0; j < 8; ++j) {
      int h = c8 + j;
      int kc = row ^ (((h >> 3) & 7) << 3);
      Vt[h * 72 + kc] = v[j];
    }
  }
  __syncthreads();

  f32x4 e[4] = {};
#pragma unroll
  for (int kk = 0; kk < 4; ++kk) {
#pragma unroll
    for (int nt = 0; nt < 4; ++nt) {
      f16x8 bk = *(const f16x8*)&Kl[(nt * 16 + l15) * 136 + kk * 32 + quad * 8];
      e[nt] = MFMA16(aq[kk], bk, e[nt]);
    }
  }
  // softmax: lane holds E[q = m0+quad*4+r][k = nt*16+l15]; rows span 16 lanes
  float pr[4][4];
  float rinv[4];
#pragma unroll
  for (int r = 0; r < 4; ++r) {
    float mx = fmaxf(fmaxf(e[0][r], e[1][r]), fmaxf(e[2][r], e[3][r]));
    for (int off = 1; off < 16; off <<= 1) mx = fmaxf(mx, __shfl_xor(mx, off));
    float sm = 0.f;
#pragma unroll
    for (int nt = 0; nt < 4; ++nt) {
      float pv = __expf(e[nt][r] - mx);
      pr[nt][r] = pv;
      sm += pv;
    }
    for (int off = 1; off < 16; off <<= 1) sm += __shfl_xor(sm, off);
    rinv[r] = 1.0f / sm;
  }
  __syncthreads();  // all E reads of Kl done before Al (same region) overwrite

  // P into Al (stride 72). Rows m0..m0+15 are written AND read only by this
  // wave -> no barrier needed before PV (compiler inserts lgkmcnt).
#pragma unroll
  for (int nt = 0; nt < 4; ++nt)
#pragma unroll
    for (int r = 0; r < 4; ++r)
      Al[(m0 + quad * 4 + r) * 72 + nt * 16 + l15] = (f16)(pr[nt][r] * rinv[r]);

  f32x4 o[8] = {};
#pragma unroll
  for (int kk = 0; kk < 2; ++kk) {
    f16x8 ap = *(const f16x8*)&Al[(m0 + l15) * 72 + kk * 32 + quad * 8];
#pragma unroll
    for (int nt = 0; nt < 8; ++nt) {
      int hr = nt * 16 + l15;
      int kb = (kk * 32 + quad * 8) ^ (((hr >> 3) & 7) << 3);
      f16x8 bv = *(const f16x8*)&Vt[hr * 72 + kb];
      o[nt] = MFMA16(ap, bv, o[nt]);
    }
  }
  __syncthreads();  // Vt and all waves' Al dead before Ol overwrite

  // O bounce through LDS (stride 136, XOR by (row&15)<<3 -> 2-way max) for
  // coalesced f16x8 global stores. Rows wave-private -> no barrier after.
#pragma unroll
  for (int nt = 0; nt < 8; ++nt)
#pragma unroll
    for (int r = 0; r < 4; ++r) {
      int row = m0 + quad * 4 + r;
      int col = nt * 16 + l15;
      Ol[row * 136 + (col ^ ((row & 15) << 3))] = (f16)o[nt][r];
    }
  f16* db = dst + (size_t)b * COUT * P + (size_t)s * HW;
#pragma unroll
  for (int it = 0; it < 4; ++it) {
    int c = lane + it * 64;
    int row = m0 + (c >> 4);
    int c8 = (c & 15) * 8;
    f16x8 vv = *(const f16x8*)&Ol[row * 136 + (c8 ^ ((row & 15) << 3))];
    *(f16x8*)(db + (size_t)row * P + c8) = vv;
  }
}

// ---------------------------------------------------------------------------
// Kernel 5: out projection + bias + gamma + residual.
// grid (128 ntiles, 8 b), block 256; m-tile loop (8x 64 rows) inside.
// S fragments hoisted to regs after one staging pass; W fragments converted
// from global fp32 (L2-hot, 393 KB) -> no Wl LDS, no barriers in the m-loop.
// D[row=quad*4+r -> p][col=l15 -> m]: float4 residual load + float4 store.
// ---------------------------------------------------------------------------
__global__ __launch_bounds__(256) void out_proj(
    const f16* __restrict__ ah, const f16* __restrict__ av,
    const float* __restrict__ w, const float* __restrict__ bias,
    const float* __restrict__ gamma_p, const float* __restrict__ x,
    float* __restrict__ out)
{
  __shared__ __attribute__((aligned(16))) f16 St[128 * 72];
  const int p0 = blockIdx.x * 128;
  const int b = blockIdx.y;
  const int t = threadIdx.x;
  const int lane = t & 63, wv = t >> 6;
  const int quad = lane >> 4, l15 = lane & 15;
  const int wm = (wv >> 1) * 32, wn = (wv & 1) * 64;

  // stage S = attn_h + attn_v, transposed into St[p][k] with column swizzle
  const size_t abase = (size_t)b * COUT * P + p0;
  for (int it = 0; it < 4; ++it) {
    int c = t + it * 256;              // 1024 chunks of 8
    int k = c >> 4, p8 = (c & 15) * 8;
    f16x8 a = *(const f16x8*)(ah + abase + (size_t)k * P + p8);
    f16x8 vv = *(const f16x8*)(av + abase + (size_t)k * P + p8);
#pragma unroll
    for (int j = 0; j < 8; ++j) {
      int p = p8 + j;
      int kc = k ^ (((p >> 3) & 7) << 3);
      St[p * 72 + kc] = (f16)(a[j] + vv[j]);
    }
  }
  __syncthreads();

  // hoist S fragments into registers once (St dead afterwards)
  f16x8 sf[2][4];   // [kk][p-sub]
#pragma unroll
  for (int kk = 0; kk < 2; ++kk)
#pragma unroll
    for (int ps = 0; ps < 4; ++ps) {
      int pr2 = wn + ps * 16 + l15;
      int kb = (kk * 32 + quad * 8) ^ (((pr2 >> 3) & 7) << 3);
      sf[kk][ps] = *(const f16x8*)&St[pr2 * 72 + kb];
    }

  const float g = *gamma_p;
  const float* xb = x + (size_t)b * CIN * P;
  float* ob = out + (size_t)b * CIN * P;

  for (int mt = 0; mt < 8; ++mt) {
    const int m0 = mt * 64;
    // W fragments from global fp32 (rows m0+wm+ms*16+l15, 32B per kk chunk)
    f16x8 wf[2][2];  // [kk][m-sub]
#pragma unroll
    for (int ms = 0; ms < 2; ++ms) {
      const float* wr = w + (size_t)(m0 + wm + ms * 16 + l15) * COUT;
#pragma unroll
      for (int kk = 0; kk < 2; ++kk) {
        const float4 w0 = *(const float4*)(wr + kk * 32 + quad * 8);
        const float4 w1 = *(const float4*)(wr + kk * 32 + quad * 8 + 4);
        f16x8 f;
        f[0] = (f16)w0.x; f[1] = (f16)w0.y; f[2] = (f16)w0.z; f[3] = (f16)w0.w;
        f[4] = (f16)w1.x; f[5] = (f16)w1.y; f[6] = (f16)w1.z; f[7] = (f16)w1.w;
        wf[kk][ms] = f;
      }
    }
    f32x4 acc[4][2] = {};   // [p-sub][m-sub]
#pragma unroll
    for (int kk = 0; kk < 2; ++kk)
#pragma unroll
      for (int ps = 0; ps < 4; ++ps)
#pragma unroll
        for (int ms = 0; ms < 2; ++ms)
          acc[ps][ms] = MFMA16(sf[kk][ps], wf[kk][ms], acc[ps][ms]);
#pragma unroll
    for (int ms = 0; ms < 2; ++ms) {
      int m = m0 + wm + ms * 16 + l15;
      float bi = bias[m];
#pragma unroll
      for (int ps = 0; ps < 4; ++ps) {
        int p = p0 + wn + ps * 16 + quad * 4;
        size_t idx = (size_t)m * P + p;
        const float4 xv = *(const float4*)(xb + idx);
        float4 ov;
        ov.x = g * acc[ps][ms][0] + bi + xv.x;
        ov.y = g * acc[ps][ms][1] + bi + xv.y;
        ov.z = g * acc[ps][ms][2] + bi + xv.z;
        ov.w = g * acc[ps][ms][3] + bi + xv.w;
        *(float4*)(ob + idx) = ov;
      }
    }
  }
}

// ---------------------------------------------------------------------------
extern "C" void kernel_launch(void* const* d_in, const int* in_sizes, int n_in,
                              void* d_out, int out_size, void* d_ws,
                              size_t ws_size, hipStream_t stream)
{
  (void)in_sizes; (void)n_in; (void)out_size; (void)ws_size;
  const float* x = (const float*)d_in[0];
  const float* qkv_w = (const float*)d_in[1];
  const float* qkv_b = (const float*)d_in[2];
  const float* out_w = (const float*)d_in[3];
  const float* out_b = (const float*)d_in[4];
  const float* gamma = (const float*)d_in[5];
  float* out = (float*)d_out;

  char* ws = (char*)d_ws;
  const size_t QKV_BYTES = (size_t)8 * QKV_CH * P * sizeof(f16);   // 48 MiB
  const size_t ATT_BYTES = (size_t)8 * COUT * P * sizeof(f16);     // 16 MiB
  f16* qkv  = (f16*)ws;
  f16* qkvT = (f16*)(ws + QKV_BYTES);
  f16* ahT  = (f16*)(ws + 2 * QKV_BYTES);
  f16* ahN  = (f16*)(ws + 2 * QKV_BYTES + ATT_BYTES);
  f16* avN  = (f16*)(ws + 2 * QKV_BYTES + 2 * ATT_BYTES);

  qkv_gemm<<<dim3(128, 8), 256, 0, stream>>>(x, qkv_w, qkv_b, qkv);
  transpose_hw<<<dim3(8 * QKV_CH, 2, 2), 256, 0, stream>>>(qkv, qkvT);
  cc_attn<<<dim3(128, 8, 2), 256, 0, stream>>>(qkvT, qkv, ahT, avN);
  transpose_hw<<<dim3(8 * COUT, 2, 2), 256, 0, stream>>>(ahT, ahN);
  out_proj<<<dim3(128, 8), 256, 0, stream>>>(ahN, avN, out_w, out_b, gamma,
                                             x, out);
}